// Round 3
// baseline (1434.944 us; speedup 1.0000x reference)
//
#include <hip/hip_runtime.h>
#include <hip/hip_bf16.h>

// CharDecoder: T=21, B=4096, H=1024, E=50, V=96
// d_out: scores(T,B,V) fp32 | h_T(B,H) | c_T(B,H)

#define T_STEPS 21
#define BSZ 4096
#define HDIM 1024
#define VOCAB 96
#define EDIM 50

typedef __attribute__((ext_vector_type(8))) short short8;
typedef __attribute__((ext_vector_type(4))) short shortx4;
typedef __attribute__((ext_vector_type(4))) float f32x4;

#define GLL16(g, l)                                                        \
  __builtin_amdgcn_global_load_lds(                                        \
      (const __attribute__((address_space(1))) void*)(g),                  \
      (__attribute__((address_space(3))) void*)(l), 16, 0, 0)

#define ASM_BARRIER() asm volatile("s_barrier" ::: "memory")
#define ASM_VMCNT4() asm volatile("s_waitcnt vmcnt(4)" ::: "memory")
#define ASM_VMCNT0() asm volatile("s_waitcnt vmcnt(0)" ::: "memory")

__device__ __forceinline__ float sigmoidf_fast(float x) {
  return 1.0f / (1.0f + __expf(-x));
}
__device__ __forceinline__ float tanhf_fast(float x) {
  return 2.0f / (1.0f + __expf(-2.0f * x)) - 1.0f;
}
__device__ __forceinline__ float b2f(short s) {
  return __uint_as_float(((unsigned int)(unsigned short)s) << 16);
}

// ---- prep: fp32 -> bf16 weight/state conversion -------------------------
__global__ void prep_convert(const float* __restrict__ Whh_f,
                             const float* __restrict__ Wout_f,
                             const float* __restrict__ h0,
                             __hip_bfloat16* __restrict__ Whh,
                             __hip_bfloat16* __restrict__ Wout,
                             __hip_bfloat16* __restrict__ hb0) {
  int idx = blockIdx.x * 256 + threadIdx.x;
  if (idx < 4 * HDIM * HDIM) {
    Whh[idx] = __float2bfloat16(Whh_f[idx]);
    hb0[idx] = __float2bfloat16(h0[idx]);
  }
  if (idx < VOCAB * HDIM) Wout[idx] = __float2bfloat16(Wout_f[idx]);
}

// ---- prep: Pb[j>>6][v][unit 64][gate 4] (bf16) = emb.W_ih + b_ih + b_hh -
// gate-contiguous per unit so the epilogue gathers one ds_read_b64.
__global__ void prep_ptable(const float* __restrict__ emb,
                            const float* __restrict__ Wih,
                            const float* __restrict__ bih,
                            const float* __restrict__ bhh,
                            __hip_bfloat16* __restrict__ Pb) {
  int idx = blockIdx.x * 256 + threadIdx.x;  // 96*4096
  int v = idx >> 12, g = idx & 4095;         // g = gate*1024 + j
  int gate = g >> 10, j = g & 1023;
  const float* er = emb + v * EDIM;
  const float* wr = Wih + g * EDIM;
  float s = bih[g] + bhh[g];
#pragma unroll 10
  for (int e = 0; e < EDIM; ++e) s += er[e] * wr[e];
  Pb[(size_t)(j >> 6) * 24576 + v * 256 + (j & 63) * 4 + gate] =
      __float2bfloat16(s);
}

// ---- 256x256 8-phase LSTM step ------------------------------------------
// Tile: 256 batch rows x (4 gates x 64 units); BK=64; 8 waves (2M x 4N);
// LDS 128 KiB = 2 buffers x (A 256x64 + B 256x64) bf16.
// Phase order (mh,nh): (0,0)->(0,1)->(1,1)->(1,0) with cross-phase register
// reuse: loads per phase = 12/4/8/0 ds_read_b128 (a0 reused ph1-2, b1
// ph2-3, a1 ph3-4, b0 held ph1->ph4). One counted vmcnt(4) per K-tile;
// vmcnt(0) only at k==14. NO sched_barrier(0) (m141: order-pinning costs).
// Region discipline: stage into a region only after its last LDS read's
// end barrier:
//   ph1 stages A-h1(nb): last read iter k-1 ph3  -> safe
//   ph2 stages B-h1(nb): last read iter k-1 ph2  -> safe
//   ph3 stages A-h0(b):  last read this iter ph1 -> safe
//   ph4 stages B-h0(b):  last read this iter ph1 -> safe
// vmcnt proof: at iter k ph4, outstanding = [A1,B1](k+1), [A0,B0](k+2);
// vmcnt(4) drains the 4 oldest -> tile k+1 fully landed before iter k+1.

#define STAGE_A(h, kt, b)                                                   \
  do {                                                                      \
    GLL16(hprev + aSrc[0] + (size_t)(h) * 131072 + (size_t)(kt) * 64,       \
          smem + ((b) << 16) + ((h) << 14) + aDst[0]);                      \
    GLL16(hprev + aSrc[1] + (size_t)(h) * 131072 + (size_t)(kt) * 64,       \
          smem + ((b) << 16) + ((h) << 14) + aDst[1]);                      \
  } while (0)

#define STAGE_B(h, kt, b)                                                   \
  do {                                                                      \
    GLL16(Whh + bSrc[h][0] + (size_t)(kt) * 64,                             \
          smem + ((b) << 16) + bDst[h][0]);                                 \
    GLL16(Whh + bSrc[h][1] + (size_t)(kt) * 64,                             \
          smem + ((b) << 16) + bDst[h][1]);                                 \
  } while (0)

#define LOAD_A(dst, mh)                                                     \
  _Pragma("unroll") for (int mi2 = 0; mi2 < 4; ++mi2) {                     \
    dst[mi2] = *(const short8*)&cA[((mh) * 128 + wr * 64 + mi2 * 16 +       \
                                    u16) * 64 + sl0];                       \
    dst[4 + mi2] = *(const short8*)&cA[((mh) * 128 + wr * 64 + mi2 * 16 +   \
                                        u16) * 64 + sl1];                   \
  }

#define LOAD_B(dst, nh)                                                     \
  _Pragma("unroll") for (int ni2 = 0; ni2 < 2; ++ni2) {                     \
    dst[ni2] = *(const short8*)&cB[(wc * 64 + (nh) * 32 + ni2 * 16 +        \
                                    u16) * 64 + sl0];                       \
    dst[2 + ni2] = *(const short8*)&cB[(wc * 64 + (nh) * 32 + ni2 * 16 +    \
                                        u16) * 64 + sl1];                   \
  }

#define MFMA_Q(mh, nh, A, Bv)                                               \
  do {                                                                      \
    __builtin_amdgcn_s_setprio(1);                                          \
    _Pragma("unroll") for (int mi2 = 0; mi2 < 4; ++mi2)                     \
        _Pragma("unroll") for (int ni2 = 0; ni2 < 2; ++ni2) {               \
      acc[(mh) * 4 + mi2][(nh) * 2 + ni2] =                                 \
          __builtin_amdgcn_mfma_f32_16x16x32_bf16(                          \
              A[mi2], Bv[ni2], acc[(mh) * 4 + mi2][(nh) * 2 + ni2],         \
              0, 0, 0);                                                     \
      acc[(mh) * 4 + mi2][(nh) * 2 + ni2] =                                 \
          __builtin_amdgcn_mfma_f32_16x16x32_bf16(                          \
              A[4 + mi2], Bv[2 + ni2],                                      \
              acc[(mh) * 4 + mi2][(nh) * 2 + ni2], 0, 0, 0);                \
    }                                                                       \
    __builtin_amdgcn_s_setprio(0);                                          \
  } while (0)

template <bool LAST>
__global__ __launch_bounds__(512, 2) void lstm_step_kernel(
    const int* __restrict__ ids,               // B ints (this t)
    const __hip_bfloat16* __restrict__ hprev,  // B x H
    const __hip_bfloat16* __restrict__ Whh,    // 4H x H (torch order i,f,g,o)
    const __hip_bfloat16* __restrict__ Pb,     // 16 x 96 x 64 x 4 (bf16)
    const float* __restrict__ c_in,            // B x H
    float* __restrict__ c_out,                 // B x H
    __hip_bfloat16* __restrict__ hnext,        // B x H
    float* __restrict__ hf32)                  // B x H (LAST only)
{
  __shared__ __align__(16) char smem[131072];

  const int tid = threadIdx.x;
  const int wid = tid >> 6;
  const int lane = tid & 63;
  const int wr = wid >> 2;  // 0..1  (M half of wave grid)
  const int wc = wid & 3;   // 0..3  (N quarter)
  const int u16 = lane & 15;
  const int k16q = lane >> 4;
  const int u7 = u16 & 7;
  const int sl0 = (k16q ^ u7) * 8;        // kk=0..31 slot
  const int sl1 = ((4 + k16q) ^ u7) * 8;  // kk=32..63 slot

  // XCD-bijective swizzle: the 16 jt-blocks sharing an A panel (same mt
  // pair) land on one XCD -> A stays in that XCD's L2.
  const int bid = blockIdx.x;
  const int mt = (bid & 7) * 2 + ((bid >> 3) & 1);  // 0..15
  const int jt = bid >> 4;                          // 0..15 (64-unit block)
  const int m0 = mt * 256;

  // staging lane decomposition: 8 rows x 8 swizzled 16B slots per GLL16
  const int lrow = lane >> 3;
  const int swcol = ((lane & 7) ^ lrow) * 8;

  // per-thread staging bases. A group g = wid*2+q covers LDS rows
  // h*128 + g*8 .. +8. B group g covers LDS rows R..R+8 with
  // R = (g>>2)*64 + h*32 + (g&3)*8  (stripe sets: half h = rows w/ bit5==h).
  size_t aSrc[2];
  size_t bSrc[2][2];
  int aDst[2];
  int bDst[2][2];
#pragma unroll
  for (int q = 0; q < 2; ++q) {
    const int g = wid * 2 + q;
    aSrc[q] = (size_t)(m0 + g * 8 + lrow) * HDIM + swcol;
    aDst[q] = g * 1024;
#pragma unroll
    for (int h = 0; h < 2; ++h) {
      const int R = (g >> 2) * 64 + h * 32 + (g & 3) * 8;
      const int n = R + lrow;  // LDS B row
      const int gate = (n >> 4) & 3;
      const int uo = (n >> 6) * 16 + (n & 15);
      bSrc[h][q] = (size_t)(gate * HDIM + jt * 64 + uo) * HDIM + swcol;
      bDst[h][q] = 32768 + R * 128;
    }
  }

  // prologue: K-tile 0 fully, then c prefetch, then A0/B0 of K-tile 1
  STAGE_A(0, 0, 0);
  STAGE_B(0, 0, 0);
  STAGE_A(1, 0, 0);
  STAGE_B(1, 0, 0);

  const int jcol = jt * 64 + wc * 16 + u16;  // output unit j
  float cpre[8][4];
#pragma unroll
  for (int mi = 0; mi < 8; ++mi)
#pragma unroll
    for (int r = 0; r < 4; ++r)
      cpre[mi][r] = c_in[(size_t)(m0 + (mi >> 2) * 128 + wr * 64 +
                                  (mi & 3) * 16 + k16q * 4 + r) *
                             HDIM +
                         jcol];

  STAGE_A(0, 1, 1);
  STAGE_B(0, 1, 1);

  ASM_VMCNT4();  // K-tile 0 + cpre landed; A0/B0(1) may stay in flight
  ASM_BARRIER();

  f32x4 acc[8][4] = {};  // [M-frag][gate]

#pragma unroll 2
  for (int k = 0; k < 16; ++k) {
    const int b = k & 1;
    const int nb = b ^ 1;
    const __hip_bfloat16* cA = (const __hip_bfloat16*)(smem + (b << 16));
    const __hip_bfloat16* cB =
        (const __hip_bfloat16*)(smem + (b << 16) + 32768);
    short8 a0[8], a1[8], b0[4], b1[4];

    // ph1 (0,0): load a0 + b0
    LOAD_A(a0, 0);
    LOAD_B(b0, 0);
    if (k < 15) STAGE_A(1, k + 1, nb);
    ASM_BARRIER();
    MFMA_Q(0, 0, a0, b0);
    ASM_BARRIER();

    // ph2 (0,1): reuse a0, load b1
    LOAD_B(b1, 1);
    if (k < 15) STAGE_B(1, k + 1, nb);
    ASM_BARRIER();
    MFMA_Q(0, 1, a0, b1);
    ASM_BARRIER();

    // ph3 (1,1): load a1, reuse b1
    LOAD_A(a1, 1);
    if (k < 14) STAGE_A(0, k + 2, b);
    ASM_BARRIER();
    MFMA_Q(1, 1, a1, b1);
    ASM_BARRIER();

    // ph4 (1,0): reuse a1, reuse b0 (no LDS reads)
    if (k < 14) STAGE_B(0, k + 2, b);
    ASM_BARRIER();
    MFMA_Q(1, 0, a1, b0);
    if (k < 14) {
      ASM_VMCNT4();  // all of K-tile k+1 landed; 2 half-tiles in flight
    } else if (k == 14) {
      ASM_VMCNT0();  // drain tail (ph3/ph4 stages were skipped)
    }
    ASM_BARRIER();
  }

  // stage bf16 P slice (48 KB) into now-dead LDS; no GLL16s outstanding.
  {
    const __hip_bfloat16* Pbj = Pb + (size_t)jt * 24576;
#pragma unroll
    for (int i = 0; i < 6; ++i)
      GLL16(Pbj + (wid * 6 + i) * 512 + lane * 8,
            smem + (wid * 6 + i) * 1024);
  }
  ASM_VMCNT0();
  ASM_BARRIER();

  // epilogue: all 4 gates of unit jcol contiguous -> one b64 gather
  const __hip_bfloat16* sPb = (const __hip_bfloat16*)smem;
  const int uo4 = (wc * 16 + u16) * 4;
  const int rb = m0 + wr * 64 + k16q * 4;
#pragma unroll
  for (int mi = 0; mi < 8; ++mi) {
#pragma unroll
    for (int r = 0; r < 4; ++r) {
      const int row = rb + (mi >> 2) * 128 + (mi & 3) * 16 + r;
      const int id = ids[row];
      const shortx4 pv = *(const shortx4*)&sPb[id * 256 + uo4];
      float iv = acc[mi][0][r] + b2f(pv[0]);
      float fv = acc[mi][1][r] + b2f(pv[1]);
      float gv = acc[mi][2][r] + b2f(pv[2]);
      float ov = acc[mi][3][r] + b2f(pv[3]);
      iv = sigmoidf_fast(iv);
      fv = sigmoidf_fast(fv);
      gv = tanhf_fast(gv);
      ov = sigmoidf_fast(ov);
      const size_t off = (size_t)row * HDIM + jcol;
      const float cc = fv * cpre[mi][r] + iv * gv;
      c_out[off] = cc;
      const float hh = ov * tanhf_fast(cc);
      hnext[off] = __float2bfloat16(hh);
      if (LAST) hf32[off] = hh;
    }
  }
}

// ---- scores: LDS-tiled GEMM, 128 rows x 96 cols per block, BK=128 -------
__global__ __launch_bounds__(256, 2) void scores_kernel(
    const __hip_bfloat16* __restrict__ h,     // rows x H (bf16)
    const __hip_bfloat16* __restrict__ Wout,  // 96 x H
    const float* __restrict__ bout,           // 96
    float* __restrict__ out)                  // rows x 96
{
  __shared__ __align__(16) __hip_bfloat16 sA[128 * 128];  // 32 KB
  __shared__ __align__(16) __hip_bfloat16 sB[96 * 128];   // 24 KB

  const int tid = threadIdx.x;
  const int wave = tid >> 6, lane = tid & 63;
  const int u16 = lane & 15, k16q = lane >> 4;
  const long r0 = (long)blockIdx.x * 128;

  f32x4 acc[2][6] = {};  // wave: 32 rows x 96 cols

  const int srow4 = lane >> 4;  // staging: row within group of 4
  const int sslot = lane & 15;  // 16B slot within 256B row-chunk

  for (int k0 = 0; k0 < HDIM; k0 += 128) {
#pragma unroll
    for (int i = 0; i < 8; ++i) {  // A: 32 rows/wave
      int row = wave * 32 + i * 4 + srow4;
      int gg = sslot ^ (row & 15);
      GLL16(h + (r0 + row) * HDIM + k0 + gg * 8,
            &sA[(wave * 32 + i * 4) * 128]);
    }
#pragma unroll
    for (int i = 0; i < 6; ++i) {  // B: 24 rows/wave
      int row = wave * 24 + i * 4 + srow4;
      int gg = sslot ^ (row & 15);
      GLL16(Wout + (size_t)row * HDIM + k0 + gg * 8,
            &sB[(wave * 24 + i * 4) * 128]);
    }
    __syncthreads();
#pragma unroll
    for (int kk = 0; kk < 128; kk += 32) {
      const int sl = (((kk >> 3) + k16q) ^ u16) * 8;
      short8 af[2], bf[6];
#pragma unroll
      for (int mi = 0; mi < 2; ++mi)
        af[mi] = *(const short8*)&sA[(wave * 32 + mi * 16 + u16) * 128 + sl];
#pragma unroll
      for (int ni = 0; ni < 6; ++ni)
        bf[ni] = *(const short8*)&sB[(ni * 16 + u16) * 128 + sl];
#pragma unroll
      for (int mi = 0; mi < 2; ++mi)
#pragma unroll
        for (int ni = 0; ni < 6; ++ni)
          acc[mi][ni] = __builtin_amdgcn_mfma_f32_16x16x32_bf16(
              af[mi], bf[ni], acc[mi][ni], 0, 0, 0);
    }
    __syncthreads();
  }

#pragma unroll
  for (int ni = 0; ni < 6; ++ni) {
    int v = ni * 16 + u16;
    float bv = bout[v];
#pragma unroll
    for (int mi = 0; mi < 2; ++mi)
#pragma unroll
      for (int r = 0; r < 4; ++r) {
        long grow = r0 + wave * 32 + mi * 16 + k16q * 4 + r;
        out[grow * VOCAB + v] = acc[mi][ni][r] + bv;
      }
  }
}

extern "C" void kernel_launch(void* const* d_in, const int* in_sizes, int n_in,
                              void* d_out, int out_size, void* d_ws,
                              size_t ws_size, hipStream_t stream) {
  const int* ids = (const int*)d_in[0];
  const float* h0 = (const float*)d_in[1];
  const float* c0 = (const float*)d_in[2];
  const float* emb = (const float*)d_in[3];
  const float* Wih = (const float*)d_in[4];
  const float* Whh_f = (const float*)d_in[5];
  const float* bih = (const float*)d_in[6];
  const float* bhh = (const float*)d_in[7];
  const float* Wout_f = (const float*)d_in[8];
  const float* bout = (const float*)d_in[9];

  float* out = (float*)d_out;
  float* scores = out;                              // T*B*V
  float* hT = out + (size_t)T_STEPS * BSZ * VOCAB;  // B*H
  float* cT = hT + (size_t)BSZ * HDIM;              // B*H

  const size_t BH = (size_t)BSZ * HDIM;
  char* w = (char*)d_ws;
  __hip_bfloat16* Pb = (__hip_bfloat16*)w;   w += (size_t)16 * 24576 * 2;
  __hip_bfloat16* Whh = (__hip_bfloat16*)w;  w += (size_t)4 * HDIM * HDIM * 2;
  __hip_bfloat16* Wout = (__hip_bfloat16*)w; w += (size_t)VOCAB * HDIM * 2;
  __hip_bfloat16* hts = (__hip_bfloat16*)w;  // 22*BH (full) or 2*BH (pingpong)
  size_t base = (size_t)16 * 24576 * 2 + (size_t)4 * HDIM * HDIM * 2 +
                (size_t)VOCAB * HDIM * 2;
  const bool full = ws_size >= base + (size_t)(T_STEPS + 1) * BH * 2;

  prep_convert<<<dim3((4 * HDIM * HDIM + 255) / 256), dim3(256), 0, stream>>>(
      Whh_f, Wout_f, h0, Whh, Wout, hts);
  prep_ptable<<<dim3((VOCAB * 4096) / 256), dim3(256), 0, stream>>>(
      emb, Wih, bih, bhh, Pb);

  for (int t = 0; t < T_STEPS; ++t) {
    __hip_bfloat16* hp = hts + (full ? (size_t)t * BH : (size_t)(t & 1) * BH);
    __hip_bfloat16* hn =
        hts + (full ? (size_t)(t + 1) * BH : (size_t)((t + 1) & 1) * BH);
    const float* cin = (t == 0) ? c0 : cT;
    if (t == T_STEPS - 1) {
      lstm_step_kernel<true><<<dim3(256), dim3(512), 0, stream>>>(
          ids + (size_t)t * BSZ, hp, Whh, Pb, cin, cT, hn, hT);
    } else {
      lstm_step_kernel<false><<<dim3(256), dim3(512), 0, stream>>>(
          ids + (size_t)t * BSZ, hp, Whh, Pb, cin, cT, hn, nullptr);
    }
    if (!full) {
      scores_kernel<<<dim3(BSZ / 128), dim3(256), 0, stream>>>(
          hn, Wout, bout, scores + (size_t)t * BSZ * VOCAB);
    }
  }
  if (full) {
    scores_kernel<<<dim3(T_STEPS * BSZ / 128), dim3(256), 0, stream>>>(
        hts + BH, Wout, bout, scores);
  }
}

// Round 4
// 1162.409 us; speedup vs baseline: 1.2345x; 1.2345x over previous
//
#include <hip/hip_runtime.h>
#include <hip/hip_bf16.h>

// CharDecoder: T=21, B=4096, H=1024, E=50, V=96
// d_out: scores(T,B,V) fp32 | h_T(B,H) | c_T(B,H)

#define T_STEPS 21
#define BSZ 4096
#define HDIM 1024
#define VOCAB 96
#define EDIM 50

typedef __attribute__((ext_vector_type(8))) short short8;
typedef __attribute__((ext_vector_type(4))) short shortx4;
typedef __attribute__((ext_vector_type(4))) float f32x4;

#define GLL16(g, l)                                                        \
  __builtin_amdgcn_global_load_lds(                                        \
      (const __attribute__((address_space(1))) void*)(g),                  \
      (__attribute__((address_space(3))) void*)(l), 16, 0, 0)

#define ASM_BARRIER() asm volatile("s_barrier" ::: "memory")
#define ASM_VMCNT4() asm volatile("s_waitcnt vmcnt(4)" ::: "memory")
#define ASM_VMCNT0() asm volatile("s_waitcnt vmcnt(0)" ::: "memory")

__device__ __forceinline__ float sigmoidf_fast(float x) {
  return 1.0f / (1.0f + __expf(-x));
}
__device__ __forceinline__ float tanhf_fast(float x) {
  return 2.0f / (1.0f + __expf(-2.0f * x)) - 1.0f;
}
__device__ __forceinline__ float b2f(short s) {
  return __uint_as_float(((unsigned int)(unsigned short)s) << 16);
}

// ---- prep: fp32 -> bf16 weight/state conversion -------------------------
__global__ void prep_convert(const float* __restrict__ Whh_f,
                             const float* __restrict__ Wout_f,
                             const float* __restrict__ h0,
                             __hip_bfloat16* __restrict__ Whh,
                             __hip_bfloat16* __restrict__ Wout,
                             __hip_bfloat16* __restrict__ hb0) {
  int idx = blockIdx.x * 256 + threadIdx.x;
  if (idx < 4 * HDIM * HDIM) {
    Whh[idx] = __float2bfloat16(Whh_f[idx]);
    hb0[idx] = __float2bfloat16(h0[idx]);
  }
  if (idx < VOCAB * HDIM) Wout[idx] = __float2bfloat16(Wout_f[idx]);
}

// ---- prep: Pb[j>>6][v][unit 64][gate 4] (bf16) = emb.W_ih + b_ih + b_hh -
// gate-contiguous per unit so the epilogue gathers one ds_read_b64.
__global__ void prep_ptable(const float* __restrict__ emb,
                            const float* __restrict__ Wih,
                            const float* __restrict__ bih,
                            const float* __restrict__ bhh,
                            __hip_bfloat16* __restrict__ Pb) {
  int idx = blockIdx.x * 256 + threadIdx.x;  // 96*4096
  int v = idx >> 12, g = idx & 4095;         // g = gate*1024 + j
  int gate = g >> 10, j = g & 1023;
  const float* er = emb + v * EDIM;
  const float* wr = Wih + g * EDIM;
  float s = bih[g] + bhh[g];
#pragma unroll 10
  for (int e = 0; e < EDIM; ++e) s += er[e] * wr[e];
  Pb[(size_t)(j >> 6) * 24576 + v * 256 + (j & 63) * 4 + gate] =
      __float2bfloat16(s);
}

// ---- 256x256 8-phase LSTM step ------------------------------------------
// Tile: 256 batch rows x (4 gates x 64 units); BK=64; 8 waves (2M x 4N);
// LDS 128 KiB = 2 buffers x (A 256x64 + B 256x64) bf16.
// Phase order (mh,nh): (0,0)->(0,1)->(1,0)->(1,1); each phase reads its
// 12 fragments FRESH (transient regs, dead after the phase's MFMA) --
// register budget: 128 acc + ~48 transient + addresses < 256 unified.
// No sched_barrier(0) (m141), no cpre held across the loop (spill source
// found in R3: WRITE_SIZE 67MB vs 25MB ideal).
// Stage plan (2 GLL16 per phase):
//   ph1 stages A-h1(k+1,nb): nb A1 last read iter k-1 ph4  -> safe
//   ph2 stages B-h1(k+1,nb): nb B1 last read iter k-1 ph4  -> safe
//   ph3 stages A-h0(k+2,b):  cur A0 last read this iter ph2 -> safe
//   ph4 stages B-h0(k+2,b):  cur B0 last read this iter ph3 -> safe
// vmcnt proof: at iter-k ph4 vmcnt(4), outstanding = {A0,B0}(k+1) [from
// iter k-1 ph3/4] + {A1,B1}(k+1) + {A0,B0}(k+2); drains all but the 4
// newest -> tile k+1 fully landed; {A0,B0}(k+2) stay in flight.

#define STAGE_A(h, kt, b)                                                   \
  do {                                                                      \
    GLL16(hprev + aSrc[0] + (size_t)(h) * 131072 + (size_t)(kt) * 64,       \
          smem + ((b) << 16) + ((h) << 14) + aDst[0]);                      \
    GLL16(hprev + aSrc[1] + (size_t)(h) * 131072 + (size_t)(kt) * 64,       \
          smem + ((b) << 16) + ((h) << 14) + aDst[1]);                      \
  } while (0)

#define STAGE_B(h, kt, b)                                                   \
  do {                                                                      \
    GLL16(Whh + bSrc[h][0] + (size_t)(kt) * 64,                             \
          smem + ((b) << 16) + bDst[h][0]);                                 \
    GLL16(Whh + bSrc[h][1] + (size_t)(kt) * 64,                             \
          smem + ((b) << 16) + bDst[h][1]);                                 \
  } while (0)

#define PHASE(mh, nh, STAGE_STMT, VM_STMT)                                  \
  {                                                                         \
    short8 af[8], bf[4];                                                    \
    _Pragma("unroll") for (int mi2 = 0; mi2 < 4; ++mi2) {                   \
      af[mi2] = *(const short8*)&cA[((mh) * 128 + wr * 64 + mi2 * 16 +      \
                                     u16) * 64 + sl0];                      \
      af[4 + mi2] = *(const short8*)&cA[((mh) * 128 + wr * 64 + mi2 * 16 +  \
                                         u16) * 64 + sl1];                  \
    }                                                                       \
    _Pragma("unroll") for (int ni2 = 0; ni2 < 2; ++ni2) {                   \
      bf[ni2] = *(const short8*)&cB[(wc * 64 + (nh) * 32 + ni2 * 16 +       \
                                     u16) * 64 + sl0];                      \
      bf[2 + ni2] = *(const short8*)&cB[(wc * 64 + (nh) * 32 + ni2 * 16 +   \
                                         u16) * 64 + sl1];                  \
    }                                                                       \
    STAGE_STMT;                                                             \
    ASM_BARRIER();                                                          \
    __builtin_amdgcn_s_setprio(1);                                          \
    _Pragma("unroll") for (int mi2 = 0; mi2 < 4; ++mi2)                     \
        _Pragma("unroll") for (int ni2 = 0; ni2 < 2; ++ni2) {               \
      acc[(mh) * 4 + mi2][(nh) * 2 + ni2] =                                 \
          __builtin_amdgcn_mfma_f32_16x16x32_bf16(                          \
              af[mi2], bf[ni2], acc[(mh) * 4 + mi2][(nh) * 2 + ni2],        \
              0, 0, 0);                                                     \
      acc[(mh) * 4 + mi2][(nh) * 2 + ni2] =                                 \
          __builtin_amdgcn_mfma_f32_16x16x32_bf16(                          \
              af[4 + mi2], bf[2 + ni2],                                     \
              acc[(mh) * 4 + mi2][(nh) * 2 + ni2], 0, 0, 0);                \
    }                                                                       \
    __builtin_amdgcn_s_setprio(0);                                          \
    VM_STMT;                                                                \
    ASM_BARRIER();                                                          \
  }

template <bool LAST>
__global__ __launch_bounds__(512, 2) void lstm_step_kernel(
    const int* __restrict__ ids,               // B ints (this t)
    const __hip_bfloat16* __restrict__ hprev,  // B x H
    const __hip_bfloat16* __restrict__ Whh,    // 4H x H (torch order i,f,g,o)
    const __hip_bfloat16* __restrict__ Pb,     // 16 x 96 x 64 x 4 (bf16)
    const float* __restrict__ c_in,            // B x H
    float* __restrict__ c_out,                 // B x H
    __hip_bfloat16* __restrict__ hnext,        // B x H
    float* __restrict__ hf32)                  // B x H (LAST only)
{
  __shared__ __align__(16) char smem[131072];

  const int tid = threadIdx.x;
  const int wid = tid >> 6;
  const int lane = tid & 63;
  const int wr = wid >> 2;  // 0..1  (M half of wave grid)
  const int wc = wid & 3;   // 0..3  (N quarter)
  const int u16 = lane & 15;
  const int k16q = lane >> 4;
  const int u7 = u16 & 7;
  const int sl0 = (k16q ^ u7) * 8;        // kk=0..31 slot
  const int sl1 = ((4 + k16q) ^ u7) * 8;  // kk=32..63 slot

  // XCD-bijective swizzle: the 16 jt-blocks sharing an A panel (same mt)
  // land on one XCD -> A stays in that XCD's L2.
  const int bid = blockIdx.x;
  const int mt = (bid & 7) * 2 + ((bid >> 3) & 1);  // 0..15
  const int jt = bid >> 4;                          // 0..15 (64-unit block)
  const int m0 = mt * 256;

  // staging lane decomposition: 8 rows x 8 swizzled 16B slots per GLL16
  const int lrow = lane >> 3;
  const int swcol = ((lane & 7) ^ lrow) * 8;

  // per-thread staging bases. A group g = wid*2+q covers LDS rows
  // h*128 + g*8 .. +8. B group g covers LDS rows R..R+8 with
  // R = (g>>2)*64 + h*32 + (g&3)*8  (stripe sets: half h = rows w/ bit5==h).
  size_t aSrc[2];
  size_t bSrc[2][2];
  int aDst[2];
  int bDst[2][2];
#pragma unroll
  for (int q = 0; q < 2; ++q) {
    const int g = wid * 2 + q;
    aSrc[q] = (size_t)(m0 + g * 8 + lrow) * HDIM + swcol;
    aDst[q] = g * 1024;
#pragma unroll
    for (int h = 0; h < 2; ++h) {
      const int R = (g >> 2) * 64 + h * 32 + (g & 3) * 8;
      const int n = R + lrow;  // LDS B row
      const int gate = (n >> 4) & 3;
      const int uo = (n >> 6) * 16 + (n & 15);
      bSrc[h][q] = (size_t)(gate * HDIM + jt * 64 + uo) * HDIM + swcol;
      bDst[h][q] = 32768 + R * 128;
    }
  }

  // prologue: K-tile 0 fully, then A0/B0 of K-tile 1
  STAGE_A(0, 0, 0);
  STAGE_B(0, 0, 0);
  STAGE_A(1, 0, 0);
  STAGE_B(1, 0, 0);
  STAGE_A(0, 1, 1);
  STAGE_B(0, 1, 1);

  ASM_VMCNT4();  // K-tile 0 landed; A0/B0(1) may stay in flight
  ASM_BARRIER();

  f32x4 acc[8][4] = {};  // [M-frag][gate]

#pragma unroll 2
  for (int k = 0; k < 16; ++k) {
    const int b = k & 1;
    const int nb = b ^ 1;
    const __hip_bfloat16* cA = (const __hip_bfloat16*)(smem + (b << 16));
    const __hip_bfloat16* cB =
        (const __hip_bfloat16*)(smem + (b << 16) + 32768);

    PHASE(0, 0, { if (k < 15) STAGE_A(1, k + 1, nb); }, {});
    PHASE(0, 1, { if (k < 15) STAGE_B(1, k + 1, nb); }, {});
    PHASE(1, 0, { if (k < 14) STAGE_A(0, k + 2, b); }, {});
    PHASE(1, 1, { if (k < 14) STAGE_B(0, k + 2, b); }, {
      if (k < 14) {
        ASM_VMCNT4();  // tile k+1 fully landed; {A0,B0}(k+2) in flight
      } else if (k == 14) {
        ASM_VMCNT0();  // drain tail (ph3/ph4 stages were skipped)
      }
    });
  }

  // c_in prefetch (overlaps Pb staging + barrier below). Each block owns a
  // disjoint (row, jcol) tile of c, so load-then-store is race-free.
  const int jcol = jt * 64 + wc * 16 + u16;  // output unit j
  float cpre[8][4];
#pragma unroll
  for (int mi = 0; mi < 8; ++mi)
#pragma unroll
    for (int r = 0; r < 4; ++r)
      cpre[mi][r] = c_in[(size_t)(m0 + (mi >> 2) * 128 + wr * 64 +
                                  (mi & 3) * 16 + k16q * 4 + r) *
                             HDIM +
                         jcol];

  // stage bf16 P slice (48 KB) into now-dead LDS; no GLL16s outstanding.
  {
    const __hip_bfloat16* Pbj = Pb + (size_t)jt * 24576;
#pragma unroll
    for (int i = 0; i < 6; ++i)
      GLL16(Pbj + (wid * 6 + i) * 512 + lane * 8,
            smem + (wid * 6 + i) * 1024);
  }
  ASM_VMCNT0();
  ASM_BARRIER();

  // epilogue: all 4 gates of unit jcol contiguous -> one b64 gather
  const __hip_bfloat16* sPb = (const __hip_bfloat16*)smem;
  const int uo4 = (wc * 16 + u16) * 4;
  const int rb = m0 + wr * 64 + k16q * 4;
#pragma unroll
  for (int mi = 0; mi < 8; ++mi) {
#pragma unroll
    for (int r = 0; r < 4; ++r) {
      const int row = rb + (mi >> 2) * 128 + (mi & 3) * 16 + r;
      const int id = ids[row];
      const shortx4 pv = *(const shortx4*)&sPb[id * 256 + uo4];
      float iv = acc[mi][0][r] + b2f(pv[0]);
      float fv = acc[mi][1][r] + b2f(pv[1]);
      float gv = acc[mi][2][r] + b2f(pv[2]);
      float ov = acc[mi][3][r] + b2f(pv[3]);
      iv = sigmoidf_fast(iv);
      fv = sigmoidf_fast(fv);
      gv = tanhf_fast(gv);
      ov = sigmoidf_fast(ov);
      const size_t off = (size_t)row * HDIM + jcol;
      const float cc = fv * cpre[mi][r] + iv * gv;
      c_out[off] = cc;
      const float hh = ov * tanhf_fast(cc);
      hnext[off] = __float2bfloat16(hh);
      if (LAST) hf32[off] = hh;
    }
  }
}

// ---- scores: LDS-tiled GEMM, 128 rows x 96 cols per block, BK=128 -------
__global__ __launch_bounds__(256, 2) void scores_kernel(
    const __hip_bfloat16* __restrict__ h,     // rows x H (bf16)
    const __hip_bfloat16* __restrict__ Wout,  // 96 x H
    const float* __restrict__ bout,           // 96
    float* __restrict__ out)                  // rows x 96
{
  __shared__ __align__(16) __hip_bfloat16 sA[128 * 128];  // 32 KB
  __shared__ __align__(16) __hip_bfloat16 sB[96 * 128];   // 24 KB

  const int tid = threadIdx.x;
  const int wave = tid >> 6, lane = tid & 63;
  const int u16 = lane & 15, k16q = lane >> 4;
  const long r0 = (long)blockIdx.x * 128;

  f32x4 acc[2][6] = {};  // wave: 32 rows x 96 cols

  const int srow4 = lane >> 4;  // staging: row within group of 4
  const int sslot = lane & 15;  // 16B slot within 256B row-chunk

  for (int k0 = 0; k0 < HDIM; k0 += 128) {
#pragma unroll
    for (int i = 0; i < 8; ++i) {  // A: 32 rows/wave
      int row = wave * 32 + i * 4 + srow4;
      int gg = sslot ^ (row & 15);
      GLL16(h + (r0 + row) * HDIM + k0 + gg * 8,
            &sA[(wave * 32 + i * 4) * 128]);
    }
#pragma unroll
    for (int i = 0; i < 6; ++i) {  // B: 24 rows/wave
      int row = wave * 24 + i * 4 + srow4;
      int gg = sslot ^ (row & 15);
      GLL16(Wout + (size_t)row * HDIM + k0 + gg * 8,
            &sB[(wave * 24 + i * 4) * 128]);
    }
    __syncthreads();
#pragma unroll
    for (int kk = 0; kk < 128; kk += 32) {
      const int sl = (((kk >> 3) + k16q) ^ u16) * 8;
      short8 af[2], bf[6];
#pragma unroll
      for (int mi = 0; mi < 2; ++mi)
        af[mi] = *(const short8*)&sA[(wave * 32 + mi * 16 + u16) * 128 + sl];
#pragma unroll
      for (int ni = 0; ni < 6; ++ni)
        bf[ni] = *(const short8*)&sB[(ni * 16 + u16) * 128 + sl];
#pragma unroll
      for (int mi = 0; mi < 2; ++mi)
#pragma unroll
        for (int ni = 0; ni < 6; ++ni)
          acc[mi][ni] = __builtin_amdgcn_mfma_f32_16x16x32_bf16(
              af[mi], bf[ni], acc[mi][ni], 0, 0, 0);
    }
    __syncthreads();
  }

#pragma unroll
  for (int ni = 0; ni < 6; ++ni) {
    int v = ni * 16 + u16;
    float bv = bout[v];
#pragma unroll
    for (int mi = 0; mi < 2; ++mi)
#pragma unroll
      for (int r = 0; r < 4; ++r) {
        long grow = r0 + wave * 32 + mi * 16 + k16q * 4 + r;
        out[grow * VOCAB + v] = acc[mi][ni][r] + bv;
      }
  }
}

extern "C" void kernel_launch(void* const* d_in, const int* in_sizes, int n_in,
                              void* d_out, int out_size, void* d_ws,
                              size_t ws_size, hipStream_t stream) {
  const int* ids = (const int*)d_in[0];
  const float* h0 = (const float*)d_in[1];
  const float* c0 = (const float*)d_in[2];
  const float* emb = (const float*)d_in[3];
  const float* Wih = (const float*)d_in[4];
  const float* Whh_f = (const float*)d_in[5];
  const float* bih = (const float*)d_in[6];
  const float* bhh = (const float*)d_in[7];
  const float* Wout_f = (const float*)d_in[8];
  const float* bout = (const float*)d_in[9];

  float* out = (float*)d_out;
  float* scores = out;                              // T*B*V
  float* hT = out + (size_t)T_STEPS * BSZ * VOCAB;  // B*H
  float* cT = hT + (size_t)BSZ * HDIM;              // B*H

  const size_t BH = (size_t)BSZ * HDIM;
  char* w = (char*)d_ws;
  __hip_bfloat16* Pb = (__hip_bfloat16*)w;   w += (size_t)16 * 24576 * 2;
  __hip_bfloat16* Whh = (__hip_bfloat16*)w;  w += (size_t)4 * HDIM * HDIM * 2;
  __hip_bfloat16* Wout = (__hip_bfloat16*)w; w += (size_t)VOCAB * HDIM * 2;
  __hip_bfloat16* hts = (__hip_bfloat16*)w;  // 22*BH (full) or 2*BH (pingpong)
  size_t base = (size_t)16 * 24576 * 2 + (size_t)4 * HDIM * HDIM * 2 +
                (size_t)VOCAB * HDIM * 2;
  const bool full = ws_size >= base + (size_t)(T_STEPS + 1) * BH * 2;

  prep_convert<<<dim3((4 * HDIM * HDIM + 255) / 256), dim3(256), 0, stream>>>(
      Whh_f, Wout_f, h0, Whh, Wout, hts);
  prep_ptable<<<dim3((VOCAB * 4096) / 256), dim3(256), 0, stream>>>(
      emb, Wih, bih, bhh, Pb);

  for (int t = 0; t < T_STEPS; ++t) {
    __hip_bfloat16* hp = hts + (full ? (size_t)t * BH : (size_t)(t & 1) * BH);
    __hip_bfloat16* hn =
        hts + (full ? (size_t)(t + 1) * BH : (size_t)((t + 1) & 1) * BH);
    const float* cin = (t == 0) ? c0 : cT;
    if (t == T_STEPS - 1) {
      lstm_step_kernel<true><<<dim3(256), dim3(512), 0, stream>>>(
          ids + (size_t)t * BSZ, hp, Whh, Pb, cin, cT, hn, hT);
    } else {
      lstm_step_kernel<false><<<dim3(256), dim3(512), 0, stream>>>(
          ids + (size_t)t * BSZ, hp, Whh, Pb, cin, cT, hn, nullptr);
    }
    if (!full) {
      scores_kernel<<<dim3(BSZ / 128), dim3(256), 0, stream>>>(
          hn, Wout, bout, scores + (size_t)t * BSZ * VOCAB);
    }
  }
  if (full) {
    scores_kernel<<<dim3(T_STEPS * BSZ / 128), dim3(256), 0, stream>>>(
        hts + BH, Wout, bout, scores);
  }
}